// Round 9
// baseline (146.994 us; speedup 1.0000x reference)
//
#include <hip/hip_runtime.h>
#include <stdint.h>

#define NPRED 2048
#define MT    512
#define BLK   256
#define NCAND 512
#define REC   2176   // per-batch ws: srt[512]u16 | prs[512]u16 | meta[8]i32

#define M_NPOS  0
#define M_NT    1
#define M_K     2
#define M_FIRST 3

template<int C>
__device__ __forceinline__ uint32_t dppminu(uint32_t v) {
  uint32_t o = (uint32_t)__builtin_amdgcn_update_dpp((int)v, (int)v, C, 0xF, 0xF, false);
  return v < o ? v : o;
}
__device__ __forceinline__ uint32_t wave_min_u32_l63(uint32_t v) {
  v = dppminu<0x111>(v); v = dppminu<0x112>(v); v = dppminu<0x114>(v);
  v = dppminu<0x118>(v); v = dppminu<0x142>(v); v = dppminu<0x143>(v);
  return (uint32_t)__builtin_amdgcn_readlane((int)v, 63);
}
__device__ __forceinline__ uint32_t rowmin16(uint32_t v) {  // lane15/31/47/63 hold row min
  v = dppminu<0x111>(v); v = dppminu<0x112>(v);
  v = dppminu<0x114>(v); v = dppminu<0x118>(v);
  return v;
}
__device__ __forceinline__ float wave_sum_f32(float v) {
#pragma unroll
  for (int off = 32; off; off >>= 1) v += __shfl_xor(v, off, 64);
  return v;
}

// ---------------- K1: select + rank-sort + prob loss ----------------
__global__ __launch_bounds__(BLK) void prep_kernel(const float* __restrict__ preds,
                                                   const float* __restrict__ targets,
                                                   uint8_t* __restrict__ recs,
                                                   double* __restrict__ acc) {
  const int b = blockIdx.x;
  const float* __restrict__ P = preds   + (size_t)b * NPRED * 5;
  const float* __restrict__ T = targets + (size_t)b * MT * 5;
  uint16_t* __restrict__ srt = (uint16_t*)(recs + (size_t)b * REC);
  int* __restrict__ meta = (int*)(recs + (size_t)b * REC + 2048);

  __shared__ uint64_t keys[NPRED];   // 16 KB
  __shared__ uint64_t cand[NCAND];   // 4 KB
  __shared__ int hist[256];
  __shared__ int s_npos, s_nt, s_B, s_ncand;
  __shared__ uint64_t s_thr;

  const int tid = threadIdx.x;
  if (tid == 0) { s_npos = 0; s_nt = 0; s_B = 0; s_ncand = 0; s_thr = 0ull; }
  hist[tid] = 0;
  __syncthreads();

  int cpos = 0;
  for (int i = tid; i < NPRED; i += BLK) {
    float c = P[i * 5 + 0];
    cpos += (c > 0.5f) ? 1 : 0;
    uint32_t cb = __float_as_uint(c);
    keys[i] = ((uint64_t)(~cb) << 32) | (uint32_t)i;   // asc key == conf desc, idx asc
    if (cb >= 0x3F000000u && cb < 0x3F800000u)
      atomicAdd(&hist[(cb >> 15) & 0xFF], 1);
  }
  atomicAdd(&s_npos, cpos);

  int ct = 0;
  for (int m = tid; m < MT; m += BLK) ct += (T[m * 5 + 0] == 1.0f) ? 1 : 0;
  atomicAdd(&s_nt, ct);
  __syncthreads();
  const int n_pos = s_npos;
  const int n_targs = s_nt;

  // wave0: suffix-scan histogram -> cutoff bucket B
  if (tid < 64) {
    const int lane = tid;
    int4 h4 = *reinterpret_cast<const int4*>(&hist[lane * 4]);
    int t = h4.x + h4.y + h4.z + h4.w;
    int S = t;
#pragma unroll
    for (int off = 1; off < 64; off <<= 1) {
      int o = __shfl_down(S, off);
      if (lane + off < 64) S += o;
    }
    int Snext = S - t;
    int s3 = h4.w + Snext;
    int s2 = h4.z + s3;
    int s1 = h4.y + s2;
    int s0 = h4.x + s1;
    int localB = -1;
    if      (s3 >= n_targs) localB = lane * 4 + 3;
    else if (s2 >= n_targs) localB = lane * 4 + 2;
    else if (s1 >= n_targs) localB = lane * 4 + 1;
    else if (s0 >= n_targs) localB = lane * 4 + 0;
    uint64_t q = __ballot(localB >= 0);
    if (q) {
      int hl = 63 - __clzll((long long)q);
      int B = __builtin_amdgcn_readlane(localB, hl);
      if (lane == 0) s_B = B;
    }
  }
  for (int i = tid; i < NCAND; i += BLK) srt[i] = 0;
  __syncthreads();
  const int B = s_B;

  for (int i = tid; i < NPRED; i += BLK) {
    uint64_t k = keys[i];
    uint32_t cb = ~(uint32_t)(k >> 32);
    if (cb >= 0x3F000000u && cb < 0x3F800000u && (int)((cb >> 15) & 0xFF) >= B) {
      int slot = atomicAdd(&s_ncand, 1);
      if (slot < NCAND) cand[slot] = k;
    }
  }
  __syncthreads();
  const int ncand = min(s_ncand, NCAND);

  // rank-sort: rank = # smaller keys; scatter pred index by rank
  {
    uint64_t ka = (tid < ncand) ? cand[tid] : ~0ull;
    uint64_t kb = (tid + BLK < ncand) ? cand[tid + BLK] : ~0ull;
    int ra = 0, rb = 0;
    for (int j = 0; j < ncand; ++j) {
      uint64_t kj = cand[j];
      ra += (kj < ka) ? 1 : 0;
      rb += (kj < kb) ? 1 : 0;
    }
    if (tid < ncand) {
      srt[ra] = (uint16_t)(ka & 0xFFFFu);
      if (ra == n_targs - 1) s_thr = ka;
    }
    if (tid + BLK < ncand) {
      srt[rb] = (uint16_t)(kb & 0xFFFFu);
      if (rb == n_targs - 1) s_thr = kb;
    }
  }
  __syncthreads();
  const uint64_t thr = s_thr;

  // prob loss: t = (key <= thr); wave-level reduce, no barriers
  float accp = 0.f;
  for (int i = tid; i < NPRED; i += BLK) {
    uint64_t k = keys[i];
    float p = __uint_as_float(~(uint32_t)(k >> 32));
    accp += (k <= thr) ? -fmaxf(logf(p), -100.0f)
                       : -fmaxf(log1pf(-p), -100.0f);
  }
  accp = wave_sum_f32(accp);
  if ((tid & 63) == 0) atomicAdd(&acc[4], (double)accp);

  if (tid == 0) {
    meta[M_NPOS] = n_pos;
    meta[M_NT]   = n_targs;
    meta[M_K]    = min(n_pos, n_targs);
  }
}

// ---------------- K2: 4-pred group-split greedy match (1 wave) ----------------
__global__ __launch_bounds__(64) void match_kernel(const float* __restrict__ preds,
                                                   const float* __restrict__ targets,
                                                   uint8_t* __restrict__ recs) {
  const int b = blockIdx.x;
  const int lane = threadIdx.x;
  const float* __restrict__ P = preds   + (size_t)b * NPRED * 5;
  const float* __restrict__ T = targets + (size_t)b * MT * 5;
  const uint16_t* __restrict__ srt = (const uint16_t*)(recs + (size_t)b * REC);
  uint16_t* __restrict__ prs = (uint16_t*)(recs + (size_t)b * REC + 1024);
  int* __restrict__ meta = (int*)(recs + (size_t)b * REC + 2048);

  const int K = meta[M_K];
  const int n_targs = meta[M_NT];

  __shared__ float spx[524], spy[524];

  // stage sorted preds (pads zero)
  for (int i = lane; i < 524; i += 64) {
    if (i < n_targs) {
      int pi = srt[i];
      spx[i] = P[pi * 5 + 1];
      spy[i] = P[pi * 5 + 2];
    } else { spx[i] = 0.f; spy[i] = 0.f; }
  }

  // per-lane register targets: lane's s owns targets s*32..s*32+31
  const int s = lane & 15;
  const uint32_t sbase = (uint32_t)(s << 5);
  const int g = lane >> 4;
  float txr[32], tyr[32];
  uint32_t una = 0;   // 1 = invalid-or-used
#pragma unroll
  for (int j = 0; j < 32; ++j) {
    int base = (s * 32 + j) * 5;
    float tp = T[base + 0];
    txr[j] = T[base + 1];
    tyr[j] = T[base + 2];
    una |= (tp == 1.0f) ? 0u : (1u << j);
  }
  __syncthreads();

  int i = 0;
  float x = spx[g], y = spy[g];
  while (i + 4 <= K) {
    // prefetch all 4 possible next positions for this group
    float nx1 = spx[i + 1 + g], ny1 = spy[i + 1 + g];
    float nx2 = spx[i + 2 + g], ny2 = spy[i + 2 + g];
    float nx3 = spx[i + 3 + g], ny3 = spy[i + 3 + g];
    float nx4 = spx[i + 4 + g], ny4 = spy[i + 4 + g];

    uint32_t kk = 0xFFFFFFFFu;
#pragma unroll
    for (int j = 0; j < 32; ++j) {
      float dx = __fsub_rn(txr[j], x);
      float dy = __fsub_rn(tyr[j], y);
      float d2 = __fadd_rn(__fmul_rn(dx, dx), __fmul_rn(dy, dy));
      uint32_t pois = (uint32_t)(((int32_t)(una << (31 - j))) >> 31); // bfe_i32 pattern
      uint32_t key = (((__float_as_uint(d2) | pois) & 0xFFFFFE00u)) | (uint32_t)j;
      kk = kk < key ? kk : key;
    }
    uint32_t kkg = kk + sbase;          // low 9 bits -> global target idx (carry-free)
    kkg = rowmin16(kkg);
    uint32_t m0 = (uint32_t)__builtin_amdgcn_readlane((int)kkg, 15) & 0x1FFu;
    uint32_t m1 = (uint32_t)__builtin_amdgcn_readlane((int)kkg, 31) & 0x1FFu;
    uint32_t m2 = (uint32_t)__builtin_amdgcn_readlane((int)kkg, 47) & 0x1FFu;
    uint32_t m3 = (uint32_t)__builtin_amdgcn_readlane((int)kkg, 63) & 0x1FFu;

    // branchless distinct-prefix length p
    int p = (m1 == m0) ? 1
          : (m2 == m0 || m2 == m1) ? 2
          : (m3 == m0 || m3 == m1 || m3 == m2) ? 3 : 4;
    // neutralize non-committed picks (0x3FF decodes to word 31 != any s<16)
    uint32_t m1e = (p > 1) ? m1 : 0x3FFu;
    uint32_t m2e = (p > 2) ? m2 : 0x3FFu;
    uint32_t m3e = (p > 3) ? m3 : 0x3FFu;

    // commit: poison hit targets in this lane's word
    una |= ((m0  >> 5) == (uint32_t)s) ? (1u << (m0  & 31u)) : 0u;
    una |= ((m1e >> 5) == (uint32_t)s) ? (1u << (m1e & 31u)) : 0u;
    una |= ((m2e >> 5) == (uint32_t)s) ? (1u << (m2e & 31u)) : 0u;
    una |= ((m3e >> 5) == (uint32_t)s) ? (1u << (m3e & 31u)) : 0u;

    if (lane == 0) {
      prs[i]     = (uint16_t)m0;
      prs[i + 1] = (uint16_t)m1e;   // garbage slots overwritten by later iters
      prs[i + 2] = (uint16_t)m2e;
      prs[i + 3] = (uint16_t)m3e;
    }
    i += p;
    x = (p == 1) ? nx1 : (p == 2) ? nx2 : (p == 3) ? nx3 : nx4;
    y = (p == 1) ? ny1 : (p == 2) ? ny2 : (p == 3) ? ny3 : ny4;
  }
  // tail: single-pred steps (row 0 covers all 512 targets)
  while (i < K) {
    float x1 = spx[i], y1 = spy[i];
    uint32_t kk = 0xFFFFFFFFu;
#pragma unroll
    for (int j = 0; j < 32; ++j) {
      float dx = __fsub_rn(txr[j], x1);
      float dy = __fsub_rn(tyr[j], y1);
      float d2 = __fadd_rn(__fmul_rn(dx, dx), __fmul_rn(dy, dy));
      uint32_t pois = (uint32_t)(((int32_t)(una << (31 - j))) >> 31);
      uint32_t key = (((__float_as_uint(d2) | pois) & 0xFFFFFE00u)) | (uint32_t)j;
      kk = kk < key ? kk : key;
    }
    uint32_t kkg = rowmin16(kk + sbase);
    uint32_t m = (uint32_t)__builtin_amdgcn_readlane((int)kkg, 15) & 0x1FFu;
    una |= ((m >> 5) == (uint32_t)s) ? (1u << (m & 31u)) : 0u;
    if (lane == 0) prs[i] = (uint16_t)m;
    ++i;
  }
  // first valid unused target
  uint32_t av = ~una;
  uint32_t fi = av ? (sbase + (uint32_t)__ffs(av) - 1u) : 0xFFFFFFFFu;
  fi = wave_min_u32_l63(fi);
  if (lane == 0) meta[M_FIRST] = (fi < MT) ? (int)fi : 0;
}

// ---------------- K3: deferred MSE + case_first ----------------
__global__ __launch_bounds__(BLK) void mse_kernel(const float* __restrict__ preds,
                                                  const float* __restrict__ targets,
                                                  const uint8_t* __restrict__ recs,
                                                  double* __restrict__ acc) {
  const int b = blockIdx.x;
  const int tid = threadIdx.x;
  const float* __restrict__ P = preds   + (size_t)b * NPRED * 5;
  const float* __restrict__ T = targets + (size_t)b * MT * 5;
  const uint16_t* __restrict__ srt = (const uint16_t*)(recs + (size_t)b * REC);
  const uint16_t* __restrict__ prs = (const uint16_t*)(recs + (size_t)b * REC + 1024);
  const int* __restrict__ meta = (const int*)(recs + (size_t)b * REC + 2048);
  const int n_pos = meta[M_NPOS], n_targs = meta[M_NT];
  const int K = meta[M_K], first = meta[M_FIRST];

  float ax = 0.f, ay = 0.f, aa = 0.f, ab = 0.f;

  for (int r = tid; r < K; r += BLK) {
    int m = prs[r];
    int pi = srt[r];
    float dx = __fsub_rn(P[pi * 5 + 1], T[m * 5 + 1]);
    float dy = __fsub_rn(P[pi * 5 + 2], T[m * 5 + 2]);
    float da = __fsub_rn(P[pi * 5 + 3], T[m * 5 + 3]);
    float db = __fsub_rn(P[pi * 5 + 4], T[m * 5 + 4]);
    ax += __fmul_rn(dx, dx);
    ay += __fmul_rn(dy, dy);
    aa += __fmul_rn(da, da);
    ab += __fmul_rn(db, db);
  }
  if (n_pos < n_targs) {
    float fx = T[first * 5 + 1], fy = T[first * 5 + 2];
    float fa = T[first * 5 + 3], fb = T[first * 5 + 4];
    for (int r = n_pos + tid; r < n_targs; r += BLK) {
      int pi = srt[r];
      float dx = __fsub_rn(P[pi * 5 + 1], fx);
      float dy = __fsub_rn(P[pi * 5 + 2], fy);
      float da = __fsub_rn(P[pi * 5 + 3], fa);
      float db = __fsub_rn(P[pi * 5 + 4], fb);
      ax += __fmul_rn(dx, dx);
      ay += __fmul_rn(dy, dy);
      aa += __fmul_rn(da, da);
      ab += __fmul_rn(db, db);
    }
  }
  ax = wave_sum_f32(ax);
  ay = wave_sum_f32(ay);
  aa = wave_sum_f32(aa);
  ab = wave_sum_f32(ab);
  if ((tid & 63) == 0) {
    atomicAdd(&acc[0], (double)ax);
    atomicAdd(&acc[1], (double)ay);
    atomicAdd(&acc[2], (double)aa);
    atomicAdd(&acc[3], (double)ab);
  }
}

__global__ void finalize_kernel(const double* __restrict__ acc,
                                float* __restrict__ out, double inv) {
  int c = threadIdx.x;
  if (c < 5) out[c] = (float)(acc[c] * inv);
}

extern "C" void kernel_launch(void* const* d_in, const int* in_sizes, int n_in,
                              void* d_out, int out_size, void* d_ws, size_t ws_size,
                              hipStream_t stream) {
  const float* preds = (const float*)d_in[0];
  const float* targets = (const float*)d_in[1];
  int B = in_sizes[0] / (NPRED * 5);

  double* acc = (double*)d_ws;
  uint8_t* recs = (uint8_t*)d_ws + 64;

  hipMemsetAsync(acc, 0, 5 * sizeof(double), stream);
  prep_kernel<<<B, BLK, 0, stream>>>(preds, targets, recs, acc);
  match_kernel<<<B, 64, 0, stream>>>(preds, targets, recs);
  mse_kernel<<<B, BLK, 0, stream>>>(preds, targets, recs, acc);
  finalize_kernel<<<1, 64, 0, stream>>>(acc, (float*)d_out,
                                        1.0 / ((double)B * NPRED));
}

// Round 10
// 143.530 us; speedup vs baseline: 1.0241x; 1.0241x over previous
//
#include <hip/hip_runtime.h>
#include <stdint.h>

#define NPRED 2048
#define MT    512
#define BLK   256
#define NCAND 512

template<int C>
__device__ __forceinline__ uint32_t dppminu(uint32_t v) {
  uint32_t o = (uint32_t)__builtin_amdgcn_update_dpp((int)v, (int)v, C, 0xF, 0xF, false);
  return v < o ? v : o;
}
__device__ __forceinline__ uint32_t wave_min_u32_l63(uint32_t v) {
  v = dppminu<0x111>(v); v = dppminu<0x112>(v); v = dppminu<0x114>(v);
  v = dppminu<0x118>(v); v = dppminu<0x142>(v); v = dppminu<0x143>(v);
  return (uint32_t)__builtin_amdgcn_readlane((int)v, 63);
}
__device__ __forceinline__ uint32_t rowmin8(uint32_t v) {  // lanes 7,15,..,63 hold 8-lane-group min
  v = dppminu<0x111>(v); v = dppminu<0x112>(v); v = dppminu<0x114>(v);
  return v;
}
__device__ __forceinline__ float wave_sum_f32(float v) {
#pragma unroll
  for (int off = 32; off; off >>= 1) v += __shfl_xor(v, off, 64);
  return v;
}

__global__ __launch_bounds__(BLK, 1) void loss_kernel(const float* __restrict__ preds,
                                                      const float* __restrict__ targets,
                                                      double* __restrict__ acc) {
  const int b = blockIdx.x;
  const float* __restrict__ P = preds   + (size_t)b * NPRED * 5;
  const float* __restrict__ T = targets + (size_t)b * MT * 5;

  __shared__ uint64_t keys[NPRED];                     // 16 KB
  __shared__ uint64_t cand[NCAND];                     // 4 KB
  __shared__ float txy[MT * 2];                        // 4 KB (tx,ty interleaved)
  __shared__ float tab[MT * 2];                        // 4 KB (ta,tb interleaved)
  __shared__ float spxy[528 * 2];                      // 4.2 KB (x,y interleaved)
  __shared__ float spab[528 * 2];                      // 4.2 KB (a,b interleaved)
  __shared__ uint16_t plds[512];                       // 1 KB
  __shared__ int hist[256];                            // 1 KB
  __shared__ uint32_t validw[16];
  __shared__ int s_npos, s_nt, s_B, s_ncand, s_first;
  __shared__ uint64_t s_thr;

  const int tid = threadIdx.x;
  if (tid == 0) { s_npos = 0; s_nt = 0; s_B = 0; s_ncand = 0; s_first = 0; s_thr = 0ull; }
  hist[tid] = 0;
  if (tid < 16) validw[tid] = 0;
  for (int i = tid; i < 528; i += BLK) {
    spxy[2 * i] = 0.f; spxy[2 * i + 1] = 0.f;
    spab[2 * i] = 0.f; spab[2 * i + 1] = 0.f;
  }
  __syncthreads();

  // ---- keys + histogram of conf in [0.5,1) + n_pos ----
  int cpos = 0;
  for (int i = tid; i < NPRED; i += BLK) {
    float c = P[i * 5 + 0];
    cpos += (c > 0.5f) ? 1 : 0;
    uint32_t cb = __float_as_uint(c);
    keys[i] = ((uint64_t)(~cb) << 32) | (uint32_t)i;   // asc key == conf desc, idx asc
    if (cb >= 0x3F000000u && cb < 0x3F800000u)
      atomicAdd(&hist[(cb >> 15) & 0xFF], 1);
  }
  atomicAdd(&s_npos, cpos);

  // ---- stage targets + validity + n_targs ----
  int ct = 0;
  for (int m = tid; m < MT; m += BLK) {
    float tp = T[m * 5 + 0];
    bool v = (tp == 1.0f);
    if (v) { ct++; atomicOr(&validw[m >> 5], 1u << (m & 31)); }
    txy[2 * m]     = T[m * 5 + 1];
    txy[2 * m + 1] = T[m * 5 + 2];
    tab[2 * m]     = T[m * 5 + 3];
    tab[2 * m + 1] = T[m * 5 + 4];
  }
  atomicAdd(&s_nt, ct);
  __syncthreads();
  const int n_pos = s_npos;
  const int n_targs = s_nt;

  // ---- wave0: suffix-scan histogram -> cutoff bucket B ----
  if (tid < 64) {
    const int lane = tid;
    int4 h4 = *reinterpret_cast<const int4*>(&hist[lane * 4]);
    int t = h4.x + h4.y + h4.z + h4.w;
    int S = t;
#pragma unroll
    for (int off = 1; off < 64; off <<= 1) {
      int o = __shfl_down(S, off);
      if (lane + off < 64) S += o;
    }
    int Snext = S - t;
    int s3 = h4.w + Snext;
    int s2 = h4.z + s3;
    int s1 = h4.y + s2;
    int s0 = h4.x + s1;
    int localB = -1;
    if      (s3 >= n_targs) localB = lane * 4 + 3;
    else if (s2 >= n_targs) localB = lane * 4 + 2;
    else if (s1 >= n_targs) localB = lane * 4 + 1;
    else if (s0 >= n_targs) localB = lane * 4 + 0;
    uint64_t q = __ballot(localB >= 0);
    if (q) {
      int hl = 63 - __clzll((long long)q);
      int B = __builtin_amdgcn_readlane(localB, hl);
      if (lane == 0) s_B = B;
    }
  }
  __syncthreads();
  const int B = s_B;

  // ---- gather candidates (bucket >= B) ----
  for (int i = tid; i < NPRED; i += BLK) {
    uint64_t k = keys[i];
    uint32_t cb = ~(uint32_t)(k >> 32);
    if (cb >= 0x3F000000u && cb < 0x3F800000u && (int)((cb >> 15) & 0xFF) >= B) {
      int slot = atomicAdd(&s_ncand, 1);
      if (slot < NCAND) cand[slot] = k;
    }
  }
  __syncthreads();
  const int ncand = min(s_ncand, NCAND);

  // ---- rank-sort: scatter pred rows by rank; thrkey at rank n_targs-1 ----
  {
    uint64_t ka = (tid < ncand) ? cand[tid] : ~0ull;
    uint64_t kb = (tid + BLK < ncand) ? cand[tid + BLK] : ~0ull;
    int ra = 0, rb = 0;
    for (int j = 0; j < ncand; ++j) {
      uint64_t kj = cand[j];
      ra += (kj < ka) ? 1 : 0;
      rb += (kj < kb) ? 1 : 0;
    }
    if (tid < ncand && ra < n_targs) {
      int idx = (int)(ka & 0xFFFFFFFFu);
      spxy[2 * ra] = P[idx * 5 + 1]; spxy[2 * ra + 1] = P[idx * 5 + 2];
      spab[2 * ra] = P[idx * 5 + 3]; spab[2 * ra + 1] = P[idx * 5 + 4];
    }
    if (tid < ncand && ra == n_targs - 1) s_thr = ka;
    if (tid + BLK < ncand && rb < n_targs) {
      int idx = (int)(kb & 0xFFFFFFFFu);
      spxy[2 * rb] = P[idx * 5 + 1]; spxy[2 * rb + 1] = P[idx * 5 + 2];
      spab[2 * rb] = P[idx * 5 + 3]; spab[2 * rb + 1] = P[idx * 5 + 4];
    }
    if (tid + BLK < ncand && rb == n_targs - 1) s_thr = kb;
  }
  __syncthreads();
  const uint64_t thr = s_thr;
  const int K = min(n_pos, n_targs);

  float accp = 0.f;

  if (tid < 64) {
    // ---- wave0: 8-pred group-split greedy match (64 targets/lane in VGPRs) ----
    const int lane = tid;
    const int s8 = lane & 7;          // target chunk: s8*64 .. s8*64+63
    const int g8 = lane >> 3;         // group -> pred i+g8
    const uint32_t sb6 = (uint32_t)(s8 << 6);

    float txr[64], tyr[64];
#pragma unroll
    for (int j = 0; j < 64; ++j) {
      txr[j] = txy[2 * (s8 * 64 + j)];
      tyr[j] = txy[2 * (s8 * 64 + j) + 1];
    }
    uint32_t una_lo = ~validw[2 * s8];       // 1 = invalid-or-used
    uint32_t una_hi = ~validw[2 * s8 + 1];

    int i = 0;
    float x = spxy[2 * g8], y = spxy[2 * g8 + 1];
    while (i + 8 <= K) {
      // prefetch the 8 possible next coords for this group
      float nx1 = spxy[2*(i+1+g8)], ny1 = spxy[2*(i+1+g8)+1];
      float nx2 = spxy[2*(i+2+g8)], ny2 = spxy[2*(i+2+g8)+1];
      float nx3 = spxy[2*(i+3+g8)], ny3 = spxy[2*(i+3+g8)+1];
      float nx4 = spxy[2*(i+4+g8)], ny4 = spxy[2*(i+4+g8)+1];
      float nx5 = spxy[2*(i+5+g8)], ny5 = spxy[2*(i+5+g8)+1];
      float nx6 = spxy[2*(i+6+g8)], ny6 = spxy[2*(i+6+g8)+1];
      float nx7 = spxy[2*(i+7+g8)], ny7 = spxy[2*(i+7+g8)+1];
      float nx8 = spxy[2*(i+8+g8)], ny8 = spxy[2*(i+8+g8)+1];

      uint32_t kk = 0xFFFFFFFFu;
#pragma unroll
      for (int j = 0; j < 64; ++j) {
        float dx = __fsub_rn(txr[j], x);
        float dy = __fsub_rn(tyr[j], y);
        float d2 = __fmaf_rn(dy, dy, __fmul_rn(dx, dx));
        uint32_t u = (j < 32) ? una_lo : una_hi;
        uint32_t pois = (uint32_t)(((int32_t)(u << (31 - (j & 31)))) >> 31);
        uint32_t key = ((__float_as_uint(d2) | pois) & 0xFFFFFE00u) | (uint32_t)j;
        kk = kk < key ? kk : key;
      }
      uint32_t kkg = rowmin8(kk + sb6);
      int m0 = __builtin_amdgcn_readlane((int)kkg, 7)  & 0x1FF;
      int m1 = __builtin_amdgcn_readlane((int)kkg, 15) & 0x1FF;
      int m2 = __builtin_amdgcn_readlane((int)kkg, 23) & 0x1FF;
      int m3 = __builtin_amdgcn_readlane((int)kkg, 31) & 0x1FF;
      int m4 = __builtin_amdgcn_readlane((int)kkg, 39) & 0x1FF;
      int m5 = __builtin_amdgcn_readlane((int)kkg, 47) & 0x1FF;
      int m6 = __builtin_amdgcn_readlane((int)kkg, 55) & 0x1FF;
      int m7 = __builtin_amdgcn_readlane((int)kkg, 63) & 0x1FF;

      // distinct-prefix length p (scalar)
      bool c1 = (m1==m0);
      bool c2 = (m2==m0)|(m2==m1);
      bool c3 = (m3==m0)|(m3==m1)|(m3==m2);
      bool c4 = (m4==m0)|(m4==m1)|(m4==m2)|(m4==m3);
      bool c5 = (m5==m0)|(m5==m1)|(m5==m2)|(m5==m3)|(m5==m4);
      bool c6 = (m6==m0)|(m6==m1)|(m6==m2)|(m6==m3)|(m6==m4)|(m6==m5);
      bool c7 = (m7==m0)|(m7==m1)|(m7==m2)|(m7==m3)|(m7==m4)|(m7==m5)|(m7==m6);
      int p = c1 ? 1 : c2 ? 2 : c3 ? 3 : c4 ? 4 : c5 ? 5 : c6 ? 6 : c7 ? 7 : 8;

      // neutralize non-committed picks (0x3FF: word 7+..no, chunk 15 != any s8<8)
      int m1e = (p > 1) ? m1 : 0x3FF;
      int m2e = (p > 2) ? m2 : 0x3FF;
      int m3e = (p > 3) ? m3 : 0x3FF;
      int m4e = (p > 4) ? m4 : 0x3FF;
      int m5e = (p > 5) ? m5 : 0x3FF;
      int m6e = (p > 6) ? m6 : 0x3FF;
      int m7e = (p > 7) ? m7 : 0x3FF;

#define COMMIT(me) { \
      uint64_t bb = 1ull << ((me) & 63); \
      bool hh = (((me) >> 6) == s8); \
      una_lo |= hh ? (uint32_t)(bb & 0xFFFFFFFFull) : 0u; \
      una_hi |= hh ? (uint32_t)(bb >> 32) : 0u; }
      COMMIT(m0) COMMIT(m1e) COMMIT(m2e) COMMIT(m3e)
      COMMIT(m4e) COMMIT(m5e) COMMIT(m6e) COMMIT(m7e)
#undef COMMIT

      if (lane == 0) {
        plds[i]     = (uint16_t)m0;
        plds[i + 1] = (uint16_t)m1e;   // garbage slots overwritten by later iters/tail
        plds[i + 2] = (uint16_t)m2e;
        plds[i + 3] = (uint16_t)m3e;
        plds[i + 4] = (uint16_t)m4e;
        plds[i + 5] = (uint16_t)m5e;
        plds[i + 6] = (uint16_t)m6e;
        plds[i + 7] = (uint16_t)m7e;
      }
      i += p;
      x = (p==1)?nx1:(p==2)?nx2:(p==3)?nx3:(p==4)?nx4:(p==5)?nx5:(p==6)?nx6:(p==7)?nx7:nx8;
      y = (p==1)?ny1:(p==2)?ny2:(p==3)?ny3:(p==4)?ny4:(p==5)?ny5:(p==6)?ny6:(p==7)?ny7:ny8;
    }
    // tail: single-pred steps (each 8-lane group covers all 512; use lane 7)
    while (i < K) {
      float x1 = spxy[2 * i], y1 = spxy[2 * i + 1];
      uint32_t kk = 0xFFFFFFFFu;
#pragma unroll
      for (int j = 0; j < 64; ++j) {
        float dx = __fsub_rn(txr[j], x1);
        float dy = __fsub_rn(tyr[j], y1);
        float d2 = __fmaf_rn(dy, dy, __fmul_rn(dx, dx));
        uint32_t u = (j < 32) ? una_lo : una_hi;
        uint32_t pois = (uint32_t)(((int32_t)(u << (31 - (j & 31)))) >> 31);
        uint32_t key = ((__float_as_uint(d2) | pois) & 0xFFFFFE00u) | (uint32_t)j;
        kk = kk < key ? kk : key;
      }
      uint32_t kkg = rowmin8(kk + sb6);
      int m = __builtin_amdgcn_readlane((int)kkg, 7) & 0x1FF;
      uint64_t bb = 1ull << (m & 63);
      bool hh = ((m >> 6) == s8);
      una_lo |= hh ? (uint32_t)(bb & 0xFFFFFFFFull) : 0u;
      una_hi |= hh ? (uint32_t)(bb >> 32) : 0u;
      if (lane == 0) plds[i] = (uint16_t)m;
      ++i;
    }
    // first valid unused target
    uint32_t avlo = ~una_lo, avhi = ~una_hi;
    uint32_t fl = avlo ? ((uint32_t)__ffs(avlo) - 1u)
                       : (avhi ? (31u + (uint32_t)__ffs(avhi)) : 0xFFFFu);
    uint32_t fi = (fl == 0xFFFFu) ? 0xFFFFFFFFu : (sb6 + fl);
    fi = wave_min_u32_l63(fi);
    if (lane == 0) s_first = (fi < MT) ? (int)fi : 0;
  } else {
    // ---- waves 1-3: prob loss (t = key <= thrkey) ----
    for (int i = tid - 64; i < NPRED; i += (BLK - 64)) {
      uint64_t k = keys[i];
      float p = __uint_as_float(~(uint32_t)(k >> 32));
      accp += (k <= thr) ? -fmaxf(logf(p), -100.0f)
                         : -fmaxf(log1pf(-p), -100.0f);
    }
  }
  __syncthreads();

  // ---- fused MSE over matched pairs + case_first ----
  float ax = 0.f, ay = 0.f, aa = 0.f, ab = 0.f;
  for (int r = tid; r < K; r += BLK) {
    int m = plds[r];
    float dx = __fsub_rn(spxy[2 * r],     txy[2 * m]);
    float dy = __fsub_rn(spxy[2 * r + 1], txy[2 * m + 1]);
    float da = __fsub_rn(spab[2 * r],     tab[2 * m]);
    float db = __fsub_rn(spab[2 * r + 1], tab[2 * m + 1]);
    ax += __fmul_rn(dx, dx);
    ay += __fmul_rn(dy, dy);
    aa += __fmul_rn(da, da);
    ab += __fmul_rn(db, db);
  }
  if (n_pos < n_targs) {
    int f = s_first;
    float fx = txy[2 * f], fy = txy[2 * f + 1];
    float fa = tab[2 * f], fb = tab[2 * f + 1];
    for (int i2 = n_pos + tid; i2 < n_targs; i2 += BLK) {
      float dx = __fsub_rn(spxy[2 * i2],     fx);
      float dy = __fsub_rn(spxy[2 * i2 + 1], fy);
      float da = __fsub_rn(spab[2 * i2],     fa);
      float db = __fsub_rn(spab[2 * i2 + 1], fb);
      ax += __fmul_rn(dx, dx);
      ay += __fmul_rn(dy, dy);
      aa += __fmul_rn(da, da);
      ab += __fmul_rn(db, db);
    }
  }
  ax = wave_sum_f32(ax);
  ay = wave_sum_f32(ay);
  aa = wave_sum_f32(aa);
  ab = wave_sum_f32(ab);
  accp = wave_sum_f32(accp);
  if ((tid & 63) == 0) {
    atomicAdd(&acc[0], (double)ax);
    atomicAdd(&acc[1], (double)ay);
    atomicAdd(&acc[2], (double)aa);
    atomicAdd(&acc[3], (double)ab);
    atomicAdd(&acc[4], (double)accp);
  }
}

__global__ void finalize_kernel(const double* __restrict__ acc,
                                float* __restrict__ out, double inv) {
  int c = threadIdx.x;
  if (c < 5) out[c] = (float)(acc[c] * inv);
}

extern "C" void kernel_launch(void* const* d_in, const int* in_sizes, int n_in,
                              void* d_out, int out_size, void* d_ws, size_t ws_size,
                              hipStream_t stream) {
  const float* preds = (const float*)d_in[0];
  const float* targets = (const float*)d_in[1];
  int B = in_sizes[0] / (NPRED * 5);

  double* acc = (double*)d_ws;
  hipMemsetAsync(acc, 0, 5 * sizeof(double), stream);
  loss_kernel<<<B, BLK, 0, stream>>>(preds, targets, acc);
  finalize_kernel<<<1, 64, 0, stream>>>(acc, (float*)d_out,
                                        1.0 / ((double)B * NPRED));
}

// Round 11
// 129.789 us; speedup vs baseline: 1.1326x; 1.1059x over previous
//
#include <hip/hip_runtime.h>
#include <stdint.h>

#define NPRED 2048
#define MT    512
#define BLK   256
#define NCAND 512

template<int C>
__device__ __forceinline__ uint32_t dppminu(uint32_t v) {
  uint32_t o = (uint32_t)__builtin_amdgcn_update_dpp((int)v, (int)v, C, 0xF, 0xF, false);
  return v < o ? v : o;
}
__device__ __forceinline__ uint32_t wave_min_u32_l63(uint32_t v) {
  v = dppminu<0x111>(v); v = dppminu<0x112>(v); v = dppminu<0x114>(v);
  v = dppminu<0x118>(v); v = dppminu<0x142>(v); v = dppminu<0x143>(v);
  return (uint32_t)__builtin_amdgcn_readlane((int)v, 63);
}
__device__ __forceinline__ uint32_t rowmin16(uint32_t v) {  // lanes 15/31/47/63 hold row min
  v = dppminu<0x111>(v); v = dppminu<0x112>(v);
  v = dppminu<0x114>(v); v = dppminu<0x118>(v);
  return v;
}
__device__ __forceinline__ float wave_sum_f32(float v) {
#pragma unroll
  for (int off = 32; off; off >>= 1) v += __shfl_xor(v, off, 64);
  return v;
}

__global__ __launch_bounds__(BLK) void loss_kernel(const float* __restrict__ preds,
                                                   const float* __restrict__ targets,
                                                   double* __restrict__ acc) {
  const int b = blockIdx.x;
  const float* __restrict__ P = preds   + (size_t)b * NPRED * 5;
  const float* __restrict__ T = targets + (size_t)b * MT * 5;

  __shared__ uint64_t keys[NPRED];                     // 16 KB
  __shared__ uint64_t cand[NCAND];                     // 4 KB
  __shared__ float txy[MT * 2];                        // 4 KB (tx,ty interleaved)
  __shared__ float tab[MT * 2];                        // 4 KB (ta,tb interleaved)
  __shared__ float spxy[524 * 2];                      // 4.2 KB (x,y interleaved)
  __shared__ float spab[524 * 2];                      // 4.2 KB (a,b interleaved)
  __shared__ uint16_t plds[512];                       // 1 KB
  __shared__ int hist[256];                            // 1 KB
  __shared__ uint32_t validw[16];
  __shared__ int s_npos, s_nt, s_B, s_ncand, s_first;
  __shared__ uint64_t s_thr;

  const int tid = threadIdx.x;
  if (tid == 0) { s_npos = 0; s_nt = 0; s_B = 0; s_ncand = 0; s_first = 0; s_thr = 0ull; }
  hist[tid] = 0;
  if (tid < 16) validw[tid] = 0;
  for (int i = tid; i < 524; i += BLK) {
    spxy[2 * i] = 0.f; spxy[2 * i + 1] = 0.f;
    spab[2 * i] = 0.f; spab[2 * i + 1] = 0.f;
  }
  __syncthreads();

  // ---- keys + histogram of conf in [0.5,1) + n_pos ----
  int cpos = 0;
  for (int i = tid; i < NPRED; i += BLK) {
    float c = P[i * 5 + 0];
    cpos += (c > 0.5f) ? 1 : 0;
    uint32_t cb = __float_as_uint(c);
    keys[i] = ((uint64_t)(~cb) << 32) | (uint32_t)i;   // asc key == conf desc, idx asc
    if (cb >= 0x3F000000u && cb < 0x3F800000u)
      atomicAdd(&hist[(cb >> 15) & 0xFF], 1);
  }
  atomicAdd(&s_npos, cpos);

  // ---- stage targets + validity + n_targs ----
  int ct = 0;
  for (int m = tid; m < MT; m += BLK) {
    float tp = T[m * 5 + 0];
    bool v = (tp == 1.0f);
    if (v) { ct++; atomicOr(&validw[m >> 5], 1u << (m & 31)); }
    txy[2 * m]     = T[m * 5 + 1];
    txy[2 * m + 1] = T[m * 5 + 2];
    tab[2 * m]     = T[m * 5 + 3];
    tab[2 * m + 1] = T[m * 5 + 4];
  }
  atomicAdd(&s_nt, ct);
  __syncthreads();
  const int n_pos = s_npos;
  const int n_targs = s_nt;

  // ---- wave0: suffix-scan histogram -> cutoff bucket B ----
  if (tid < 64) {
    const int lane = tid;
    int4 h4 = *reinterpret_cast<const int4*>(&hist[lane * 4]);
    int t = h4.x + h4.y + h4.z + h4.w;
    int S = t;
#pragma unroll
    for (int off = 1; off < 64; off <<= 1) {
      int o = __shfl_down(S, off);
      if (lane + off < 64) S += o;
    }
    int Snext = S - t;
    int s3 = h4.w + Snext;
    int s2 = h4.z + s3;
    int s1 = h4.y + s2;
    int s0 = h4.x + s1;
    int localB = -1;
    if      (s3 >= n_targs) localB = lane * 4 + 3;
    else if (s2 >= n_targs) localB = lane * 4 + 2;
    else if (s1 >= n_targs) localB = lane * 4 + 1;
    else if (s0 >= n_targs) localB = lane * 4 + 0;
    uint64_t q = __ballot(localB >= 0);
    if (q) {
      int hl = 63 - __clzll((long long)q);
      int B = __builtin_amdgcn_readlane(localB, hl);
      if (lane == 0) s_B = B;
    }
  }
  __syncthreads();
  const int B = s_B;

  // ---- gather candidates (bucket >= B) ----
  for (int i = tid; i < NPRED; i += BLK) {
    uint64_t k = keys[i];
    uint32_t cb = ~(uint32_t)(k >> 32);
    if (cb >= 0x3F000000u && cb < 0x3F800000u && (int)((cb >> 15) & 0xFF) >= B) {
      int slot = atomicAdd(&s_ncand, 1);
      if (slot < NCAND) cand[slot] = k;
    }
  }
  __syncthreads();
  const int ncand = min(s_ncand, NCAND);

  // ---- rank-sort: scatter pred rows by rank; thrkey at rank n_targs-1 ----
  {
    uint64_t ka = (tid < ncand) ? cand[tid] : ~0ull;
    uint64_t kb = (tid + BLK < ncand) ? cand[tid + BLK] : ~0ull;
    int ra = 0, rb = 0;
    for (int j = 0; j < ncand; ++j) {
      uint64_t kj = cand[j];
      ra += (kj < ka) ? 1 : 0;
      rb += (kj < kb) ? 1 : 0;
    }
    if (tid < ncand && ra < n_targs) {
      int idx = (int)(ka & 0xFFFFFFFFu);
      spxy[2 * ra] = P[idx * 5 + 1]; spxy[2 * ra + 1] = P[idx * 5 + 2];
      spab[2 * ra] = P[idx * 5 + 3]; spab[2 * ra + 1] = P[idx * 5 + 4];
    }
    if (tid < ncand && ra == n_targs - 1) s_thr = ka;
    if (tid + BLK < ncand && rb < n_targs) {
      int idx = (int)(kb & 0xFFFFFFFFu);
      spxy[2 * rb] = P[idx * 5 + 1]; spxy[2 * rb + 1] = P[idx * 5 + 2];
      spab[2 * rb] = P[idx * 5 + 3]; spab[2 * rb + 1] = P[idx * 5 + 4];
    }
    if (tid + BLK < ncand && rb == n_targs - 1) s_thr = kb;
  }
  __syncthreads();
  const uint64_t thr = s_thr;
  const int K = min(n_pos, n_targs);

  float accp = 0.f;

  if (tid < 64) {
    // ---- wave0: 4-pred group-split greedy match (32 targets/lane, slim ops) ----
    const int lane = tid;
    const int s = lane & 15;          // target chunk: s*32 .. s*32+31
    const int g = lane >> 4;          // group -> pred i+g
    const uint32_t sbase = (uint32_t)(s << 5);

    float txr[32], tyr[32];
#pragma unroll
    for (int j = 0; j < 32; ++j) {
      txr[j] = txy[2 * (s * 32 + j)];
      tyr[j] = txy[2 * (s * 32 + j) + 1];
    }
    uint32_t una = ~validw[s];        // 1 = invalid-or-used

    int i = 0;
    float x = spxy[2 * g], y = spxy[2 * g + 1];
    while (i + 4 <= K) {
      // prefetch all 4 possible next coords for this group
      float nx1 = spxy[2*(i+1+g)], ny1 = spxy[2*(i+1+g)+1];
      float nx2 = spxy[2*(i+2+g)], ny2 = spxy[2*(i+2+g)+1];
      float nx3 = spxy[2*(i+3+g)], ny3 = spxy[2*(i+3+g)+1];
      float nx4 = spxy[2*(i+4+g)], ny4 = spxy[2*(i+4+g)+1];

      // 4 independent min-accumulators (break the serial min chain)
      uint32_t k0 = 0xFFFFFFFFu, k1 = 0xFFFFFFFFu, k2 = 0xFFFFFFFFu, k3 = 0xFFFFFFFFu;
#pragma unroll
      for (int j = 0; j < 32; j += 4) {
#define KEYOP(jj, kacc) { \
        float dx = __fsub_rn(txr[jj], x); \
        float dy = __fsub_rn(tyr[jj], y); \
        float d2 = __fmaf_rn(dy, dy, __fmul_rn(dx, dx)); \
        uint32_t pois = (uint32_t)(((int32_t)(una << (31 - (jj)))) >> 31); \
        uint32_t key = ((__float_as_uint(d2) | pois) & 0xFFFFFE00u) | (uint32_t)(jj); \
        kacc = kacc < key ? kacc : key; }
        KEYOP(j + 0, k0) KEYOP(j + 1, k1) KEYOP(j + 2, k2) KEYOP(j + 3, k3)
#undef KEYOP
      }
      uint32_t ka = k0 < k1 ? k0 : k1;
      uint32_t kb = k2 < k3 ? k2 : k3;
      uint32_t kk = ka < kb ? ka : kb;
      uint32_t kkg = rowmin16(kk + sbase);   // low 9 bits -> global idx (carry-free)
      int m0 = __builtin_amdgcn_readlane((int)kkg, 15) & 0x1FF;
      int m1 = __builtin_amdgcn_readlane((int)kkg, 31) & 0x1FF;
      int m2 = __builtin_amdgcn_readlane((int)kkg, 47) & 0x1FF;
      int m3 = __builtin_amdgcn_readlane((int)kkg, 63) & 0x1FF;

      // branchless distinct-prefix length p (SALU)
      int p = (m1 == m0) ? 1
            : (m2 == m0 || m2 == m1) ? 2
            : (m3 == m0 || m3 == m1 || m3 == m2) ? 3 : 4;
      int m1e = (p > 1) ? m1 : 0x3FF;   // 0x3FF decodes to word 31 != any s<16
      int m2e = (p > 2) ? m2 : 0x3FF;
      int m3e = (p > 3) ? m3 : 0x3FF;

      // commit: poison hit targets in this lane's word
      una |= ((uint32_t)(m0  >> 5) == (uint32_t)s) ? (1u << (m0  & 31)) : 0u;
      una |= ((uint32_t)(m1e >> 5) == (uint32_t)s) ? (1u << (m1e & 31)) : 0u;
      una |= ((uint32_t)(m2e >> 5) == (uint32_t)s) ? (1u << (m2e & 31)) : 0u;
      una |= ((uint32_t)(m3e >> 5) == (uint32_t)s) ? (1u << (m3e & 31)) : 0u;

      if (lane == 0) {
        plds[i]     = (uint16_t)m0;
        plds[i + 1] = (uint16_t)m1e;   // garbage slots overwritten by later iters/tail
        plds[i + 2] = (uint16_t)m2e;
        plds[i + 3] = (uint16_t)m3e;
      }
      i += p;
      x = (p == 1) ? nx1 : (p == 2) ? nx2 : (p == 3) ? nx3 : nx4;
      y = (p == 1) ? ny1 : (p == 2) ? ny2 : (p == 3) ? ny3 : ny4;
    }
    // tail: single-pred steps (each 16-lane row covers all 512; row 0 result)
    while (i < K) {
      float x1 = spxy[2 * i], y1 = spxy[2 * i + 1];
      uint32_t k0 = 0xFFFFFFFFu, k1 = 0xFFFFFFFFu, k2 = 0xFFFFFFFFu, k3 = 0xFFFFFFFFu;
#pragma unroll
      for (int j = 0; j < 32; j += 4) {
#define KEYOP(jj, kacc) { \
        float dx = __fsub_rn(txr[jj], x1); \
        float dy = __fsub_rn(tyr[jj], y1); \
        float d2 = __fmaf_rn(dy, dy, __fmul_rn(dx, dx)); \
        uint32_t pois = (uint32_t)(((int32_t)(una << (31 - (jj)))) >> 31); \
        uint32_t key = ((__float_as_uint(d2) | pois) & 0xFFFFFE00u) | (uint32_t)(jj); \
        kacc = kacc < key ? kacc : key; }
        KEYOP(j + 0, k0) KEYOP(j + 1, k1) KEYOP(j + 2, k2) KEYOP(j + 3, k3)
#undef KEYOP
      }
      uint32_t ka = k0 < k1 ? k0 : k1;
      uint32_t kb = k2 < k3 ? k2 : k3;
      uint32_t kk = ka < kb ? ka : kb;
      uint32_t kkg = rowmin16(kk + sbase);
      int m = __builtin_amdgcn_readlane((int)kkg, 15) & 0x1FF;
      una |= ((uint32_t)(m >> 5) == (uint32_t)s) ? (1u << (m & 31)) : 0u;
      if (lane == 0) plds[i] = (uint16_t)m;
      ++i;
    }
    // first valid unused target
    uint32_t av = ~una;
    uint32_t fi = av ? (sbase + (uint32_t)__ffs(av) - 1u) : 0xFFFFFFFFu;
    fi = wave_min_u32_l63(fi);
    if (lane == 0) s_first = (fi < MT) ? (int)fi : 0;
  } else {
    // ---- waves 1-3: prob loss (t = key <= thrkey) ----
    for (int i = tid - 64; i < NPRED; i += (BLK - 64)) {
      uint64_t k = keys[i];
      float p = __uint_as_float(~(uint32_t)(k >> 32));
      accp += (k <= thr) ? -fmaxf(logf(p), -100.0f)
                         : -fmaxf(log1pf(-p), -100.0f);
    }
  }
  __syncthreads();

  // ---- fused MSE over matched pairs + case_first ----
  float ax = 0.f, ay = 0.f, aa = 0.f, ab = 0.f;
  for (int r = tid; r < K; r += BLK) {
    int m = plds[r];
    float dx = __fsub_rn(spxy[2 * r],     txy[2 * m]);
    float dy = __fsub_rn(spxy[2 * r + 1], txy[2 * m + 1]);
    float da = __fsub_rn(spab[2 * r],     tab[2 * m]);
    float db = __fsub_rn(spab[2 * r + 1], tab[2 * m + 1]);
    ax += __fmul_rn(dx, dx);
    ay += __fmul_rn(dy, dy);
    aa += __fmul_rn(da, da);
    ab += __fmul_rn(db, db);
  }
  if (n_pos < n_targs) {
    int f = s_first;
    float fx = txy[2 * f], fy = txy[2 * f + 1];
    float fa = tab[2 * f], fb = tab[2 * f + 1];
    for (int i2 = n_pos + tid; i2 < n_targs; i2 += BLK) {
      float dx = __fsub_rn(spxy[2 * i2],     fx);
      float dy = __fsub_rn(spxy[2 * i2 + 1], fy);
      float da = __fsub_rn(spab[2 * i2],     fa);
      float db = __fsub_rn(spab[2 * i2 + 1], fb);
      ax += __fmul_rn(dx, dx);
      ay += __fmul_rn(dy, dy);
      aa += __fmul_rn(da, da);
      ab += __fmul_rn(db, db);
    }
  }
  ax = wave_sum_f32(ax);
  ay = wave_sum_f32(ay);
  aa = wave_sum_f32(aa);
  ab = wave_sum_f32(ab);
  accp = wave_sum_f32(accp);
  if ((tid & 63) == 0) {
    atomicAdd(&acc[0], (double)ax);
    atomicAdd(&acc[1], (double)ay);
    atomicAdd(&acc[2], (double)aa);
    atomicAdd(&acc[3], (double)ab);
    atomicAdd(&acc[4], (double)accp);
  }
}

__global__ void finalize_kernel(const double* __restrict__ acc,
                                float* __restrict__ out, double inv) {
  int c = threadIdx.x;
  if (c < 5) out[c] = (float)(acc[c] * inv);
}

extern "C" void kernel_launch(void* const* d_in, const int* in_sizes, int n_in,
                              void* d_out, int out_size, void* d_ws, size_t ws_size,
                              hipStream_t stream) {
  const float* preds = (const float*)d_in[0];
  const float* targets = (const float*)d_in[1];
  int B = in_sizes[0] / (NPRED * 5);

  double* acc = (double*)d_ws;
  hipMemsetAsync(acc, 0, 5 * sizeof(double), stream);
  loss_kernel<<<B, BLK, 0, stream>>>(preds, targets, acc);
  finalize_kernel<<<1, 64, 0, stream>>>(acc, (float*)d_out,
                                        1.0 / ((double)B * NPRED));
}